// Round 2
// baseline (104.023 us; speedup 1.0000x reference)
//
#include <hip/hip_runtime.h>
#include <math.h>

#define NP 128
#define DIM 2048

// ---------------------------------------------------------------------------
// K1: P = var @ grad^T   [128 x 128], K = 2048
// Full 128x128 output tile per block, K split across 64 blocks (kc = 32).
// 256 threads, 8x8 outputs/thread in cyclic distribution (r = ty+16i, c = tx+16j)
// -> conflict-free LDS broadcasts and coalesced atomic epilogue.
// ---------------------------------------------------------------------------
__global__ __launch_bounds__(256) void k_pmat(const float* __restrict__ var,
                                              const float* __restrict__ grad,
                                              float* __restrict__ P) {
    __shared__ float At[32][132];   // [k][row], padded stride
    __shared__ float Bt[32][132];
    const int tid = threadIdx.x;
    const int k0  = blockIdx.x * 32;

    // stage 128 rows x 32 k of both inputs, transposed, via float4 loads
    for (int c = tid; c < 1024; c += 256) {
        const int row = c >> 3;
        const int kq  = (c & 7) << 2;
        const float4 a = *(const float4*)(var  + row * DIM + k0 + kq);
        const float4 b = *(const float4*)(grad + row * DIM + k0 + kq);
        At[kq + 0][row] = a.x; At[kq + 1][row] = a.y;
        At[kq + 2][row] = a.z; At[kq + 3][row] = a.w;
        Bt[kq + 0][row] = b.x; Bt[kq + 1][row] = b.y;
        Bt[kq + 2][row] = b.z; Bt[kq + 3][row] = b.w;
    }
    __syncthreads();

    const int tx = tid & 15;
    const int ty = tid >> 4;
    float acc[8][8] = {};

    #pragma unroll 4
    for (int kk = 0; kk < 32; ++kk) {
        float a[8], b[8];
        #pragma unroll
        for (int i = 0; i < 8; ++i) a[i] = At[kk][ty + 16 * i];
        #pragma unroll
        for (int j = 0; j < 8; ++j) b[j] = Bt[kk][tx + 16 * j];
        #pragma unroll
        for (int i = 0; i < 8; ++i)
            #pragma unroll
            for (int j = 0; j < 8; ++j)
                acc[i][j] = fmaf(a[i], b[j], acc[i][j]);
    }

    #pragma unroll
    for (int i = 0; i < 8; ++i)
        #pragma unroll
        for (int j = 0; j < 8; ++j)
            unsafeAtomicAdd(&P[(ty + 16 * i) * NP + (tx + 16 * j)], acc[i][j]);
}

// ---------------------------------------------------------------------------
// K2: dMsd[i][j] = ||P_i - P_j||^2 / 128
// block i (128 blocks), thread j (128 threads). P is 64KB -> L1/L2 resident.
// ---------------------------------------------------------------------------
__global__ __launch_bounds__(128) void k_dmsd(const float* __restrict__ P,
                                              float* __restrict__ dMsd) {
    __shared__ float Pi[NP];
    const int i = blockIdx.x;
    const int j = threadIdx.x;
    Pi[j] = P[i * NP + j];
    __syncthreads();
    float acc = 0.f;
    #pragma unroll 4
    for (int k = 0; k < NP; k += 4) {
        const float4 p = *(const float4*)&P[j * NP + k];
        const float d0 = p.x - Pi[k + 0];
        const float d1 = p.y - Pi[k + 1];
        const float d2 = p.z - Pi[k + 2];
        const float d3 = p.w - Pi[k + 3];
        acc = fmaf(d0, d0, acc);
        acc = fmaf(d1, d1, acc);
        acc = fmaf(d2, d2, acc);
        acc = fmaf(d3, d3, acc);
    }
    dMsd[i * NP + j] = acc * (1.0f / 128.0f);
}

// ---------------------------------------------------------------------------
// K3: exact median (k-th smallest, k = 8192 0-indexed, matching numpy/jax
// percentile 'nearest': round-half-even(0.5*16383) = 8192). All dMsd >= 0,
// so uint bit-pattern order == float order. 31-step bitwise binary search:
// find largest lo s.t. count(v < lo) <= k. Data lives in registers
// (1024 threads x 16 values). Writes med, 1/(2h), 1/h.
// ---------------------------------------------------------------------------
__global__ __launch_bounds__(1024) void k_median(const float* __restrict__ dMsd,
                                                 float* __restrict__ scal) {
    __shared__ unsigned warp_sums[16];
    __shared__ unsigned sh_lo;
    const int tid = threadIdx.x;
    unsigned v[16];
    #pragma unroll
    for (int u = 0; u < 16; ++u)
        v[u] = __float_as_uint(dMsd[tid + u * 1024]);
    if (tid == 0) sh_lo = 0u;
    __syncthreads();

    unsigned lo = 0u;
    for (int b = 30; b >= 0; --b) {
        const unsigned mid = lo | (1u << b);
        unsigned cnt = 0;
        #pragma unroll
        for (int u = 0; u < 16; ++u) cnt += (v[u] < mid) ? 1u : 0u;
        #pragma unroll
        for (int o = 32; o > 0; o >>= 1) cnt += __shfl_down(cnt, o);
        if ((tid & 63) == 0) warp_sums[tid >> 6] = cnt;
        __syncthreads();
        if (tid == 0) {
            unsigned total = 0;
            #pragma unroll
            for (int w = 0; w < 16; ++w) total += warp_sums[w];
            if (total <= 8192u) sh_lo = mid;
        }
        __syncthreads();
        lo = sh_lo;
    }

    if (tid == 0) {
        const float med = __uint_as_float(lo);
        const float h = med * med * (1.0f / 4.852030263919617f); // / ln(128)
        scal[0] = med;
        scal[1] = 1.0f / (2.0f * h);
        scal[2] = 1.0f / h;
    }
}

// ---------------------------------------------------------------------------
// K4: A[i][c] = kern[i][c] + (1/(128h)) * ((kern_i @ P)[c] - rowsum_i * P[i][c])
// block i, thread c. kern row built from dMsd row; rowsum via shuffle reduce.
// ---------------------------------------------------------------------------
__global__ __launch_bounds__(128) void k_amat(const float* __restrict__ P,
                                              const float* __restrict__ dMsd,
                                              const float* __restrict__ scal,
                                              float* __restrict__ A) {
    __shared__ float kern[NP];
    __shared__ float wsum[2];
    const int i = blockIdx.x;
    const int j = threadIdx.x;
    const float inv2h = scal[1];
    const float invh  = scal[2];
    const float kv = expf(-dMsd[i * NP + j] * inv2h);
    kern[j] = kv;
    float s = kv;
    #pragma unroll
    for (int o = 32; o > 0; o >>= 1) s += __shfl_down(s, o);
    if ((j & 63) == 0) wsum[j >> 6] = s;
    __syncthreads();
    const float rowsum = wsum[0] + wsum[1];
    float acc = 0.f;
    for (int m = 0; m < NP; ++m)
        acc = fmaf(kern[m], P[m * NP + j], acc);
    A[i * NP + j] = kern[j] + invh * (1.0f / 128.0f) * (acc - rowsum * P[i * NP + j]);
}

// ---------------------------------------------------------------------------
// K5: out = A @ grad   [128 x 2048], K = 128
// grid (32 col-tiles x 16 row-groups), 256 threads: 64 cols x 4 quads,
// each thread 2 rows. A tile (8x128) staged in LDS, broadcast reads.
// ---------------------------------------------------------------------------
__global__ __launch_bounds__(256) void k_out(const float* __restrict__ A,
                                             const float* __restrict__ grad,
                                             float* __restrict__ out) {
    __shared__ float Al[8][128];
    const int tid   = threadIdx.x;
    const int c     = (blockIdx.x << 6) + (tid & 63);
    const int rbase = blockIdx.y << 3;
    const int q     = tid >> 6;           // 0..3
    for (int idx = tid; idx < 1024; idx += 256)
        Al[idx >> 7][idx & 127] = A[(rbase + (idx >> 7)) * NP + (idx & 127)];
    __syncthreads();
    const int r0 = q * 2, r1 = q * 2 + 1;
    float acc0 = 0.f, acc1 = 0.f;
    for (int m = 0; m < NP; ++m) {
        const float g = grad[m * DIM + c];
        acc0 = fmaf(Al[r0][m], g, acc0);
        acc1 = fmaf(Al[r1][m], g, acc1);
    }
    out[(rbase + r0) * DIM + c] = acc0;
    out[(rbase + r1) * DIM + c] = acc1;
}

// ---------------------------------------------------------------------------
extern "C" void kernel_launch(void* const* d_in, const int* in_sizes, int n_in,
                              void* d_out, int out_size, void* d_ws, size_t ws_size,
                              hipStream_t stream) {
    const float* var  = (const float*)d_in[0];   // var_flat  [128,2048] f32
    const float* grad = (const float*)d_in[1];   // grad_flat [128,2048] f32
    float* out  = (float*)d_out;                 // [128,2048] f32

    float* P    = (float*)d_ws;                  // 16384 f32
    float* dMsd = P + NP * NP;                   // 16384 f32
    float* A    = dMsd + NP * NP;                // 16384 f32
    float* scal = A + NP * NP;                   // 3 f32

    hipMemsetAsync(P, 0, NP * NP * sizeof(float), stream);
    k_pmat  <<<dim3(64),     dim3(256),  0, stream>>>(var, grad, P);
    k_dmsd  <<<dim3(NP),     dim3(NP),   0, stream>>>(P, dMsd);
    k_median<<<dim3(1),      dim3(1024), 0, stream>>>(dMsd, scal);
    k_amat  <<<dim3(NP),     dim3(NP),   0, stream>>>(P, dMsd, scal, A);
    k_out   <<<dim3(32, 16), dim3(256),  0, stream>>>(A, grad, out);
}